// Round 8
// baseline (2527.480 us; speedup 1.0000x reference)
//
#include <hip/hip_runtime.h>
#include <math.h>

#define BB 2
#define HIDC 64
#define HWN 1024

// ---------------------------------------------------------------- weight transpose
// dst[arr] layout: [icn*9][ocn] ; src layout: [ocn][icn*9]
struct TWArgs { const float* src[5]; float* dst[5]; int icn9[5]; int osh[5]; };

__global__ __launch_bounds__(256) void transpose_w(TWArgs a) {
  const int arr = blockIdx.y;
  const int icn9 = a.icn9[arr], osh = a.osh[arr];
  const int ocn = 1 << osh;
  const float* s = a.src[arr];
  float* d = a.dst[arr];
  const int n = icn9 << osh;
  for (int i = blockIdx.x * 256 + threadIdx.x; i < n; i += gridDim.x * 256) {
    int oc = i & (ocn - 1), tt = i >> osh;
    d[i] = s[(size_t)oc * icn9 + tt];
  }
}

// ---------------------------------------------------------------- ConvLSTM cell
struct CellArgs {
  const float* x[2]; long xbs;
  const float* h[2]; const float* c[2];
  const float* w[2]; const float* bias[2];   // w = TRANSPOSED [ic*9+t][256]
  float* ho[2]; float* co[2];
};

template<int CX>
__global__ __launch_bounds__(512) void cell_kernel(CellArgs a) {
  constexpr int CT = CX + HIDC;          // total input channels (concat x,h)
  constexpr int CH = (CT + 1) / 2;       // ic split point
  __shared__ float sIn[CT * 48];         // [CT][6][8] padded rows
  __shared__ float sGa[256 * 17];        // gates partial, ic-half 0
  __shared__ float sGb[256 * 17];        // gates partial, ic-half 1
  const int tile = blockIdx.x;           // 64 tiles of 4x4
  const int b = blockIdx.y;
  const int st = blockIdx.z;
  const int ty0 = (tile >> 3) << 2, tx0 = (tile & 7) << 2;
  const float* xp = a.x[st] + (size_t)b * a.xbs;
  const float* hp = a.h[st] + (size_t)b * HIDC * HWN;

  for (int idx = threadIdx.x; idx < CT * 36; idx += 512) {
    int ic = idx / 36, pos = idx - ic * 36;
    int iy = pos / 6, ix = pos - iy * 6;
    int gy = ty0 - 1 + iy, gx = tx0 - 1 + ix;
    float v = 0.f;
    if ((unsigned)gy < 32u && (unsigned)gx < 32u) {
      v = (ic < CX) ? xp[ic * HWN + gy * 32 + gx]
                    : hp[(ic - CX) * HWN + gy * 32 + gx];
    }
    sIn[ic * 48 + iy * 8 + ix] = v;
  }
  __syncthreads();

  const int oc = threadIdx.x & 255;      // gate channel
  const int hh = threadIdx.x >> 8;       // ic half
  const int icb = hh ? CH : 0, ice = hh ? CT : CH;
  float acc[16];
#pragma unroll
  for (int p = 0; p < 16; ++p) acc[p] = 0.f;
  const float* wp = a.w[st];             // transposed: [(ic*9+t)*256 + oc]
  for (int ic = icb; ic < ice; ++ic) {
    float w9[9];
#pragma unroll
    for (int t = 0; t < 9; ++t) w9[t] = wp[(ic * 9 + t) * 256 + oc];   // coalesced
    float in[36];
#pragma unroll
    for (int iy = 0; iy < 6; ++iy) {
      float4 v4 = *(const float4*)&sIn[ic * 48 + iy * 8];
      float2 v2 = *(const float2*)&sIn[ic * 48 + iy * 8 + 4];
      in[iy * 6 + 0] = v4.x; in[iy * 6 + 1] = v4.y; in[iy * 6 + 2] = v4.z;
      in[iy * 6 + 3] = v4.w; in[iy * 6 + 4] = v2.x; in[iy * 6 + 5] = v2.y;
    }
#pragma unroll
    for (int ky = 0; ky < 3; ++ky)
#pragma unroll
      for (int kx = 0; kx < 3; ++kx) {
        const float wv = w9[ky * 3 + kx];
#pragma unroll
        for (int py = 0; py < 4; ++py)
#pragma unroll
          for (int px = 0; px < 4; ++px)
            acc[py * 4 + px] += wv * in[(py + ky) * 6 + (px + kx)];
      }
  }
  float* sGh = hh ? sGb : sGa;
#pragma unroll
  for (int p = 0; p < 16; ++p) sGh[oc * 17 + p] = acc[p];
  __syncthreads();

  const float* cp = a.c[st] + (size_t)b * HIDC * HWN;
  float* hop = a.ho[st] + (size_t)b * HIDC * HWN;
  float* cop = a.co[st] + (size_t)b * HIDC * HWN;
  const float* bias = a.bias[st];
  for (int idx = threadIdx.x; idx < HIDC * 16; idx += 512) {
    int hc = idx >> 4, p = idx & 15;
    float gi = sGa[hc * 17 + p]         + sGb[hc * 17 + p]         + bias[hc];
    float gf = sGa[(hc + 64) * 17 + p]  + sGb[(hc + 64) * 17 + p]  + bias[hc + 64];
    float go = sGa[(hc + 128) * 17 + p] + sGb[(hc + 128) * 17 + p] + bias[hc + 128];
    float gg = sGa[(hc + 192) * 17 + p] + sGb[(hc + 192) * 17 + p] + bias[hc + 192];
    gi = 1.f / (1.f + expf(-gi));
    gf = 1.f / (1.f + expf(-gf));
    go = 1.f / (1.f + expf(-go));
    gg = tanhf(gg);
    int off = hc * HWN + (ty0 + (p >> 2)) * 32 + tx0 + (p & 3);
    float cn = gf * cp[off] + gi * gg;
    cop[off] = cn;
    hop[off] = go * tanhf(cn);
  }
}

// ---------------------------------------------------------------- QKV (1x1 convs)
// Q,V written [p][64]; K written TRANSPOSED [c][1024] for L1-friendly attn reads.
struct QkvArgs {
  const float* xq[4]; const float* xkv[4];
  const float* w[4]; const float* bias[4];
  float* Q; float* K; float* V;
};

__global__ __launch_bounds__(256) void qkv_kernel(QkvArgs a) {
  __shared__ float sWt[64 * 68];         // [c][o] transposed, pad 68
  const int ptile = blockIdx.x, b = blockIdx.y;
  const int attn = blockIdx.z / 3, proj = blockIdx.z % 3;
  const float* x = (proj == 0 ? a.xq[attn] : a.xkv[attn]) + (size_t)b * HIDC * HWN;
  const float* w = a.w[attn] + proj * 64 * 64;
  const float* bias = a.bias[attn] + proj * 64;
  const size_t bb = (size_t)attn * BB + b;
  for (int i = threadIdx.x; i < 4096; i += 256) {
    int o = i >> 6, c = i & 63;
    sWt[c * 68 + o] = w[i];
  }
  __syncthreads();
  const int pq = threadIdx.x & 63, og = threadIdx.x >> 6;
  const int p0 = ptile * 64 + pq;        // lane-consecutive px -> coalesced x reads
  float acc[16];
#pragma unroll
  for (int k = 0; k < 16; ++k) acc[k] = bias[og * 16 + k];
  for (int c = 0; c < 64; ++c) {
    float xv = x[c * HWN + p0];
#pragma unroll
    for (int k = 0; k < 16; k += 4) {
      float4 wv = *(const float4*)&sWt[c * 68 + og * 16 + k];
      acc[k+0] += xv * wv.x; acc[k+1] += xv * wv.y;
      acc[k+2] += xv * wv.z; acc[k+3] += xv * wv.w;
    }
  }
  if (proj == 1) {                        // K transposed: [c][1024], coalesced columns
    float* dK = a.K + bb * HIDC * HWN;
#pragma unroll
    for (int k = 0; k < 16; ++k)
      dK[(size_t)(og * 16 + k) * HWN + p0] = acc[k];
  } else {
    float* dst = (proj == 0 ? a.Q : a.V) + bb * HWN * HIDC;
    float* d = dst + (size_t)p0 * HIDC + og * 16;
#pragma unroll
    for (int k = 0; k < 16; k += 4) {
      float4 v; v.x = acc[k]; v.y = acc[k+1]; v.z = acc[k+2]; v.w = acc[k+3];
      *(float4*)&d[k] = v;
    }
  }
}

// ---------------------------------------------------------------- flash attention (KV-split partials)
// QBLK=64, KV-split 8 (2x64 tiles/block). Q,P in LDS (32KB); K,V streamed from
// global (L1-resident 16KB tiles) to take them off the LDS pipe.
struct AttnPArgs { const float* Q; const float* Kt; const float* V; float* pbuf; };

__global__ __launch_bounds__(256) void attn_part(AttnPArgs a) {
  __shared__ float sQt[64 * 64];   // [c][r], scaled by 1/8
  __shared__ float sPt[64 * 64];   // [j][r ^ (j&7)*4]
  const int qt = blockIdx.x >> 3, ks = blockIdx.x & 7;
  const int b = blockIdx.y, at = blockIdx.z;
  const size_t bb = (size_t)at * BB + b;
  const float* Qp  = a.Q  + bb * HWN * HIDC + (size_t)qt * 64 * HIDC;
  const float* Ktp = a.Kt + bb * HIDC * HWN;    // [c][1024]
  const float* Vp  = a.V  + bb * HWN * HIDC;    // [j][c]
  const int tid = threadIdx.x;
  { // Q stage: row qr, ch-chunk qc0; bank = qr%32 (2-way, free)
    const int qr = tid & 63, qc0 = (tid >> 6) * 16;
    const float* q = Qp + qr * HIDC + qc0;
#pragma unroll
    for (int k = 0; k < 16; k += 4) {
      float4 v = *(const float4*)&q[k];
      sQt[(qc0 + k + 0) * 64 + qr] = v.x * 0.125f;
      sQt[(qc0 + k + 1) * 64 + qr] = v.y * 0.125f;
      sQt[(qc0 + k + 2) * 64 + qr] = v.z * 0.125f;
      sQt[(qc0 + k + 3) * 64 + qr] = v.w * 0.125f;
    }
  }
  const int tc = tid & 15, tr = tid >> 4;
  const int j0 = tc * 4, r0 = tr * 4;
  float m[4], l[4], o[4][4];
#pragma unroll
  for (int i = 0; i < 4; ++i) {
    m[i] = -1e30f; l[i] = 0.f;
    o[i][0] = 0; o[i][1] = 0; o[i][2] = 0; o[i][3] = 0;
  }
  __syncthreads();

  for (int kk = 0; kk < 2; ++kk) {
    const int jg = (ks * 2 + kk) * 64;           // global KV row base
    // S = (Q/8) K^T : K read as b128 from global (L1), Q broadcast from LDS
    float s[4][4];
#pragma unroll
    for (int i = 0; i < 4; ++i) { s[i][0]=0; s[i][1]=0; s[i][2]=0; s[i][3]=0; }
    const float* kp = Ktp + jg + j0;
#pragma unroll 8
    for (int c = 0; c < 64; ++c) {
      float4 q4 = *(const float4*)&sQt[c * 64 + r0];     // conflict-free bcast
      float4 k4 = *(const float4*)&kp[(size_t)c * HWN];  // 256B coalesced
      s[0][0]+=q4.x*k4.x; s[0][1]+=q4.x*k4.y; s[0][2]+=q4.x*k4.z; s[0][3]+=q4.x*k4.w;
      s[1][0]+=q4.y*k4.x; s[1][1]+=q4.y*k4.y; s[1][2]+=q4.y*k4.z; s[1][3]+=q4.y*k4.w;
      s[2][0]+=q4.z*k4.x; s[2][1]+=q4.z*k4.y; s[2][2]+=q4.z*k4.z; s[2][3]+=q4.z*k4.w;
      s[3][0]+=q4.w*k4.x; s[3][1]+=q4.w*k4.y; s[3][2]+=q4.w*k4.z; s[3][3]+=q4.w*k4.w;
    }
    // online softmax (16-lane row groups)
    float mt[4];
#pragma unroll
    for (int i = 0; i < 4; ++i)
      mt[i] = fmaxf(fmaxf(s[i][0], s[i][1]), fmaxf(s[i][2], s[i][3]));
#pragma unroll
    for (int d = 1; d < 16; d <<= 1) {
#pragma unroll
      for (int i = 0; i < 4; ++i) mt[i] = fmaxf(mt[i], __shfl_xor(mt[i], d));
    }
    float al[4];
#pragma unroll
    for (int i = 0; i < 4; ++i) {
      float mn = fmaxf(m[i], mt[i]);
      al[i] = __expf(m[i] - mn);
      m[i] = mn;
      s[i][0] = __expf(s[i][0] - mn); s[i][1] = __expf(s[i][1] - mn);
      s[i][2] = __expf(s[i][2] - mn); s[i][3] = __expf(s[i][3] - mn);
    }
    float ps[4];
#pragma unroll
    for (int i = 0; i < 4; ++i) ps[i] = s[i][0] + s[i][1] + s[i][2] + s[i][3];
#pragma unroll
    for (int d = 1; d < 16; d <<= 1) {
#pragma unroll
      for (int i = 0; i < 4; ++i) ps[i] += __shfl_xor(ps[i], d);
    }
#pragma unroll
    for (int i = 0; i < 4; ++i) {
      l[i] = l[i] * al[i] + ps[i];
      o[i][0] *= al[i]; o[i][1] *= al[i]; o[i][2] *= al[i]; o[i][3] *= al[i];
    }
    __syncthreads();                      // prev PV readers done
#pragma unroll
    for (int jj = 0; jj < 4; ++jj) {
      int j = j0 + jj;
      float4 pv; pv.x = s[0][jj]; pv.y = s[1][jj]; pv.z = s[2][jj]; pv.w = s[3][jj];
      *(float4*)&sPt[j * 64 + (r0 ^ ((j & 7) * 4))] = pv;
    }
    __syncthreads();
    // PV: V read as b128 from global (L1), P broadcast from LDS
    const float* vp = Vp + (size_t)jg * HIDC + j0;
#pragma unroll 8
    for (int j = 0; j < 64; ++j) {
      float4 p4 = *(const float4*)&sPt[j * 64 + (r0 ^ ((j & 7) * 4))];  // bcast
      float4 v4 = *(const float4*)&vp[(size_t)j * HIDC];                // 256B
      o[0][0]+=p4.x*v4.x; o[0][1]+=p4.x*v4.y; o[0][2]+=p4.x*v4.z; o[0][3]+=p4.x*v4.w;
      o[1][0]+=p4.y*v4.x; o[1][1]+=p4.y*v4.y; o[1][2]+=p4.y*v4.z; o[1][3]+=p4.y*v4.w;
      o[2][0]+=p4.z*v4.x; o[2][1]+=p4.z*v4.y; o[2][2]+=p4.z*v4.z; o[2][3]+=p4.z*v4.w;
      o[3][0]+=p4.w*v4.x; o[3][1]+=p4.w*v4.y; o[3][2]+=p4.w*v4.z; o[3][3]+=p4.w*v4.w;
    }
  }
  // partial record: [64x64 o (unnormalized)] [64 m] [64 l] = 4224 floats
  float* pb = a.pbuf + ((bb * 16 + qt) * 8 + ks) * 4224;
#pragma unroll
  for (int i = 0; i < 4; ++i) {
    float4 w; w.x = o[i][0]; w.y = o[i][1]; w.z = o[i][2]; w.w = o[i][3];
    *(float4*)&pb[(r0 + i) * 64 + j0] = w;
  }
  if (tc == 0) {
#pragma unroll
    for (int i = 0; i < 4; ++i) {
      pb[4096 + r0 + i] = m[i];
      pb[4160 + r0 + i] = l[i];
    }
  }
}

struct AttnMArgs { const float* pbuf; const float* xq[4]; float* out[4]; };

__global__ __launch_bounds__(256) void attn_merge(AttnMArgs a) {
  __shared__ float sW[8][64];
  __shared__ float sL[64];
  const int qt = blockIdx.x, b = blockIdx.y, at = blockIdx.z;
  const float* pb = a.pbuf + (((size_t)at * BB + b) * 16 + qt) * 8 * 4224;
  if (threadIdx.x < 64) {
    int r = threadIdx.x;
    float mm[8];
#pragma unroll
    for (int i = 0; i < 8; ++i) mm[i] = pb[i * 4224 + 4096 + r];
    float M = mm[0];
#pragma unroll
    for (int i = 1; i < 8; ++i) M = fmaxf(M, mm[i]);
    float L = 0.f;
#pragma unroll
    for (int i = 0; i < 8; ++i) {
      float w = __expf(mm[i] - M);
      sW[i][r] = w;
      L += pb[i * 4224 + 4160 + r] * w;
    }
    sL[r] = L;
  }
  __syncthreads();
  const int c = threadIdx.x >> 2, rg = (threadIdx.x & 3) * 16;
  const float* xq = a.xq[at] + (size_t)b * HIDC * HWN;
  float* op = a.out[at] + (size_t)b * HIDC * HWN;
  const int p0 = qt * 64 + rg;
#pragma unroll
  for (int rr4 = 0; rr4 < 16; rr4 += 4) {
    float rv[4];
#pragma unroll
    for (int k = 0; k < 4; ++k) {
      int r = rg + rr4 + k;
      float acc = 0.f;
#pragma unroll
      for (int i = 0; i < 8; ++i) acc += pb[i * 4224 + r * 64 + c] * sW[i][r];
      rv[k] = acc / sL[r];
    }
    float4 x4 = *(const float4*)&xq[(size_t)c * HWN + p0 + rr4];
    float4 res; res.x = rv[0] + x4.x; res.y = rv[1] + x4.y;
    res.z = rv[2] + x4.z; res.w = rv[3] + x4.w;
    *(float4*)&op[(size_t)c * HWN + p0 + rr4] = res;
  }
}

// ---------------------------------------------------------------- decoder
struct Dec1Args { const float* in[2]; const float* w; const float* b; float* tmp; };

__global__ __launch_bounds__(512) void dec1_kernel(Dec1Args a) {
  __shared__ float sIn[64 * 48];
  __shared__ float sHa[64 * 17];
  __shared__ float sHb[64 * 17];
  const int tile = blockIdx.x, b = blockIdx.y, st = blockIdx.z;
  const int ty0 = (tile >> 3) << 2, tx0 = (tile & 7) << 2;
  const float* ip = a.in[st] + (size_t)b * HIDC * HWN;
  for (int idx = threadIdx.x; idx < 64 * 36; idx += 512) {
    int ic = idx / 36, pos = idx - ic * 36;
    int iy = pos / 6, ix = pos - iy * 6;
    int gy = ty0 - 1 + iy, gx = tx0 - 1 + ix;
    float v = 0.f;
    if ((unsigned)gy < 32u && (unsigned)gx < 32u) v = ip[ic * HWN + gy * 32 + gx];
    sIn[ic * 48 + iy * 8 + ix] = v;
  }
  __syncthreads();
  const int oc = threadIdx.x & 63, ps = (threadIdx.x >> 6) & 3;
  const int hh = threadIdx.x >> 8;
  const int icb = hh * 32, ice = icb + 32;
  float acc0 = 0.f, acc1 = 0.f, acc2 = 0.f, acc3 = 0.f;
  const float* wp = a.w;                 // transposed [(ic*9+t)*64 + oc]
  for (int ic = icb; ic < ice; ++ic) {
    float w9[9];
#pragma unroll
    for (int t = 0; t < 9; ++t) w9[t] = wp[(ic * 9 + t) * 64 + oc];   // coalesced
    float in[18];
#pragma unroll
    for (int ry = 0; ry < 3; ++ry) {
      float4 v4 = *(const float4*)&sIn[ic * 48 + (ps + ry) * 8];
      float2 v2 = *(const float2*)&sIn[ic * 48 + (ps + ry) * 8 + 4];
      in[ry*6+0]=v4.x; in[ry*6+1]=v4.y; in[ry*6+2]=v4.z; in[ry*6+3]=v4.w;
      in[ry*6+4]=v2.x; in[ry*6+5]=v2.y;
    }
#pragma unroll
    for (int ky = 0; ky < 3; ++ky)
#pragma unroll
      for (int kx = 0; kx < 3; ++kx) {
        float wv = w9[ky * 3 + kx];
        acc0 += wv * in[ky * 6 + kx + 0];
        acc1 += wv * in[ky * 6 + kx + 1];
        acc2 += wv * in[ky * 6 + kx + 2];
        acc3 += wv * in[ky * 6 + kx + 3];
      }
  }
  float* sH = hh ? sHb : sHa;
  sH[oc * 17 + ps * 4 + 0] = acc0;
  sH[oc * 17 + ps * 4 + 1] = acc1;
  sH[oc * 17 + ps * 4 + 2] = acc2;
  sH[oc * 17 + ps * 4 + 3] = acc3;
  __syncthreads();
  float* dst = a.tmp + ((size_t)st * BB + b) * HIDC * HWN;
  for (int idx = threadIdx.x; idx < 1024; idx += 512) {
    int oc2 = idx >> 4, p = idx & 15;
    float v = sHa[oc2 * 17 + p] + sHb[oc2 * 17 + p] + a.b[oc2];
    v = fmaxf(v, 0.f);
    dst[(size_t)oc2 * HWN + (ty0 + (p >> 2)) * 32 + tx0 + (p & 3)] = v;
  }
}

struct Dec2Args { const float* tmp; const float* w; const float* b;
                  float* dst0; float* dst1; long bstr; };

__global__ __launch_bounds__(256) void dec2_kernel(Dec2Args a) {
  __shared__ float sIn[64 * 48];
  __shared__ float sW[64 * 9];
  const int tile = blockIdx.x, b = blockIdx.y, st = blockIdx.z;
  const int ty0 = (tile >> 3) << 2, tx0 = (tile & 7) << 2;
  const float* ip = a.tmp + ((size_t)st * BB + b) * HIDC * HWN;
  for (int idx = threadIdx.x; idx < 64 * 36; idx += 256) {
    int ic = idx / 36, pos = idx - ic * 36;
    int iy = pos / 6, ix = pos - iy * 6;
    int gy = ty0 - 1 + iy, gx = tx0 - 1 + ix;
    float v = 0.f;
    if ((unsigned)gy < 32u && (unsigned)gx < 32u) v = ip[ic * HWN + gy * 32 + gx];
    sIn[ic * 48 + iy * 8 + ix] = v;
  }
  for (int idx = threadIdx.x; idx < 576; idx += 256) sW[idx] = a.w[idx];
  __syncthreads();
  const int px = threadIdx.x >> 4, icg = threadIdx.x & 15;
  const int py = px >> 2, pxx = px & 3;
  float acc = 0.f;
#pragma unroll
  for (int i = 0; i < 4; ++i) {
    int ic = icg * 4 + i;
    const float* row = &sIn[ic * 48];
    const float* wv = &sW[ic * 9];
#pragma unroll
    for (int ky = 0; ky < 3; ++ky)
#pragma unroll
      for (int kx = 0; kx < 3; ++kx)
        acc += wv[ky * 3 + kx] * row[(py + ky) * 8 + pxx + kx];
  }
#pragma unroll
  for (int d = 1; d < 16; d <<= 1) acc += __shfl_xor(acc, d);
  if (icg == 0) {
    float* d = (st == 0 ? a.dst0 : a.dst1);
    d[(size_t)b * a.bstr + (ty0 + py) * 32 + tx0 + pxx] = acc + a.b[0];
  }
}

// ---------------------------------------------------------------- host
extern "C" void kernel_launch(void* const* d_in, const int* in_sizes, int n_in,
                              void* d_out, int out_size, void* d_ws, size_t ws_size,
                              hipStream_t stream) {
  (void)in_sizes; (void)n_in; (void)out_size; (void)ws_size;
  const float* x1_seq = (const float*)d_in[0];
  const float* x2_seq = (const float*)d_in[1];
  const float* c1w[2] = {(const float*)d_in[2], (const float*)d_in[4]};
  const float* c1b[2] = {(const float*)d_in[3], (const float*)d_in[5]};
  const float* c2w[2] = {(const float*)d_in[6], (const float*)d_in[8]};
  const float* c2b[2] = {(const float*)d_in[7], (const float*)d_in[9]};
  const float* sah_w = (const float*)d_in[10]; const float* sah_b = (const float*)d_in[11];
  const float* sac_w = (const float*)d_in[12]; const float* sac_b = (const float*)d_in[13];
  const float* cah_w = (const float*)d_in[14]; const float* cah_b = (const float*)d_in[15];
  const float* cac_w = (const float*)d_in[16]; const float* cac_b = (const float*)d_in[17];
  const float* dw1 = (const float*)d_in[18]; const float* db1 = (const float*)d_in[19];
  const float* dw2 = (const float*)d_in[20]; const float* db2 = (const float*)d_in[21];
  float* out = (float*)d_out;
  float* ws = (float*)d_ws;

  const size_t SPL = (size_t)BB * HIDC * HWN;   // 131072 floats
  float* h1s = ws;                // [2][SPL] states per layer
  float* c1s = h1s + 2 * SPL;
  float* h2s = c1s + 2 * SPL;
  float* c2s = h2s + 2 * SPL;
  float* hc1 = c2s + 2 * SPL;     // cell outputs
  float* cc1 = hc1 + SPL;
  float* hc2 = cc1 + SPL;
  float* cc2 = hc2 + SPL;
  float* hs1 = cc2 + SPL;         // self-attn outputs
  float* cs1 = hs1 + SPL;
  float* hs2 = cs1 + SPL;
  float* cs2 = hs2 + SPL;
  float* Qb  = cs2 + SPL;         // [4][B][1024][64]
  float* Kb  = Qb + 4 * SPL;      // [4][B][64][1024]  (transposed K)
  float* Vb  = Kb + 4 * SPL;      // [4][B][1024][64]
  float* dtmp = Vb + 4 * SPL;     // [2][B][64][1024]
  float* pbuf = dtmp + 2 * SPL;   // [4at][B][16qt][8ks][4224]  (~17.3 MB)
  float* wt10 = pbuf + (size_t)4 * BB * 16 * 8 * 4224;   // transposed weights
  float* wt11 = wt10 + 585 * 256;
  float* wt20 = wt11 + 1152 * 256;
  float* wt21 = wt20 + 585 * 256;
  float* wtd  = wt21 + 1152 * 256;   // dec1: [576][64]

  hipMemsetAsync(ws, 0, 8 * SPL * sizeof(float), stream);  // zero states

  const dim3 blk(256);
  const dim3 blk2(512);

  { // one-time weight transposes (coalesced-dst gather-src)
    TWArgs tw;
    tw.src[0] = c1w[0]; tw.dst[0] = wt10; tw.icn9[0] = 585;  tw.osh[0] = 8;
    tw.src[1] = c1w[1]; tw.dst[1] = wt11; tw.icn9[1] = 1152; tw.osh[1] = 8;
    tw.src[2] = c2w[0]; tw.dst[2] = wt20; tw.icn9[2] = 585;  tw.osh[2] = 8;
    tw.src[3] = c2w[1]; tw.dst[3] = wt21; tw.icn9[3] = 1152; tw.osh[3] = 8;
    tw.src[4] = dw1;    tw.dst[4] = wtd;  tw.icn9[4] = 576;  tw.osh[4] = 6;
    transpose_w<<<dim3(32, 5), blk, 0, stream>>>(tw);
  }

  auto attn_stage = [&](const float* q0, const float* q1, const float* q2, const float* q3,
                        const float* k0, const float* k1, const float* k2, const float* k3,
                        const float* wh, const float* bh, const float* wc, const float* bc,
                        float* o0, float* o1, float* o2, float* o3) {
    QkvArgs qa;
    qa.xq[0]=q0; qa.xq[1]=q1; qa.xq[2]=q2; qa.xq[3]=q3;
    qa.xkv[0]=k0; qa.xkv[1]=k1; qa.xkv[2]=k2; qa.xkv[3]=k3;
    qa.w[0]=wh; qa.w[1]=wc; qa.w[2]=wh; qa.w[3]=wc;
    qa.bias[0]=bh; qa.bias[1]=bc; qa.bias[2]=bh; qa.bias[3]=bc;
    qa.Q=Qb; qa.K=Kb; qa.V=Vb;
    qkv_kernel<<<dim3(16, BB, 12), blk, 0, stream>>>(qa);
    AttnPArgs ap; ap.Q=Qb; ap.Kt=Kb; ap.V=Vb; ap.pbuf=pbuf;
    attn_part<<<dim3(128, BB, 4), blk, 0, stream>>>(ap);
    AttnMArgs am; am.pbuf=pbuf;
    am.xq[0]=q0; am.xq[1]=q1; am.xq[2]=q2; am.xq[3]=q3;
    am.out[0]=o0; am.out[1]=o1; am.out[2]=o2; am.out[3]=o3;
    attn_merge<<<dim3(16, BB, 4), blk, 0, stream>>>(am);
  };

  auto decode = [&](long off1, long off2, long bstr) {
    Dec1Args d1; d1.in[0] = h1s + SPL; d1.in[1] = h2s + SPL;
    d1.w = wtd; d1.b = db1; d1.tmp = dtmp;
    dec1_kernel<<<dim3(64, BB, 2), blk2, 0, stream>>>(d1);
    Dec2Args d2; d2.tmp = dtmp; d2.w = dw2; d2.b = db2;
    d2.dst0 = out + off1; d2.dst1 = out + off2; d2.bstr = bstr;
    dec2_kernel<<<dim3(64, BB, 2), blk, 0, stream>>>(d2);
  };

  // 6 steps: 3 warm + 3 future-consuming (last future step's state is never read)
  for (int s = 0; s < 6; ++s) {
    const float *x1, *x2; long xbs;
    if (s < 3) { x1 = x1_seq + s * HWN; x2 = x2_seq + s * HWN; xbs = 3 * HWN; }
    else       { x1 = out + (s - 3) * HWN; x2 = out + 8192 + (s - 3) * HWN; xbs = 4 * HWN; }

    for (int l = 0; l < 2; ++l) {
      if (l == 1) { x1 = h1s; x2 = h2s; xbs = (long)HIDC * HWN; }  // layer-0 state (this step)
      CellArgs ca;
      ca.x[0] = x1; ca.x[1] = x2; ca.xbs = xbs;
      ca.h[0] = h1s + l * SPL; ca.h[1] = h2s + l * SPL;
      ca.c[0] = c1s + l * SPL; ca.c[1] = c2s + l * SPL;
      ca.w[0] = (l == 0) ? wt10 : wt11;
      ca.w[1] = (l == 0) ? wt20 : wt21;
      ca.bias[0] = c1b[l]; ca.bias[1] = c2b[l];
      ca.ho[0] = hc1; ca.ho[1] = hc2; ca.co[0] = cc1; ca.co[1] = cc2;
      if (l == 0) cell_kernel<1><<<dim3(64, BB, 2), blk2, 0, stream>>>(ca);
      else        cell_kernel<64><<<dim3(64, BB, 2), blk2, 0, stream>>>(ca);

      // self-attention: (h1,h1,sah) (c1,c1,sac) (h2,h2,sah) (c2,c2,sac)
      attn_stage(hc1, cc1, hc2, cc2,
                 hc1, cc1, hc2, cc2,
                 sah_w + l * 12288, sah_b + l * 192,
                 sac_w + l * 12288, sac_b + l * 192,
                 hs1, cs1, hs2, cs2);
      // cross-attention: (h1,h2,cah) (c1,c2,cac) (h2,tag_h1,cah) (c2,tag_c1,cac)
      attn_stage(hs1, cs1, hs2, cs2,
                 hs2, cs2, hs1, cs1,
                 cah_w + l * 12288, cah_b + l * 192,
                 cac_w + l * 12288, cac_b + l * 192,
                 h1s + l * SPL, c1s + l * SPL, h2s + l * SPL, c2s + l * SPL);
    }

    if (s == 0)      decode(16384,        20480,        2048);  // warm slot 0
    else if (s == 1) decode(16384 + 1024, 20480 + 1024, 2048);  // warm slot 1
    else             decode((s - 2) * HWN, 8192 + (s - 2) * HWN, 4096); // future slots
  }
}

// Round 9
// 2073.462 us; speedup vs baseline: 1.2190x; 1.2190x over previous
//
#include <hip/hip_runtime.h>
#include <math.h>

#define BB 2
#define HIDC 64
#define HWN 1024

typedef _Float16 half8 __attribute__((ext_vector_type(8)));
typedef float f32x4 __attribute__((ext_vector_type(4)));

static __device__ __forceinline__ unsigned short f2h_bits(float v) {
  _Float16 h = (_Float16)v;
  return __builtin_bit_cast(unsigned short, h);
}
static __device__ __forceinline__ float h_back(float v) {
  _Float16 h = (_Float16)v;
  return (float)h;
}

// ---------------------------------------------------------------- weight transpose
struct TWArgs { const float* src[5]; float* dst[5]; int icn9[5]; int osh[5]; };

__global__ __launch_bounds__(256) void transpose_w(TWArgs a) {
  const int arr = blockIdx.y;
  const int icn9 = a.icn9[arr], osh = a.osh[arr];
  const int ocn = 1 << osh;
  const float* s = a.src[arr];
  float* d = a.dst[arr];
  const int n = icn9 << osh;
  for (int i = blockIdx.x * 256 + threadIdx.x; i < n; i += gridDim.x * 256) {
    int oc = i & (ocn - 1), tt = i >> osh;
    d[i] = s[(size_t)oc * icn9 + tt];
  }
}

// ---------------------------------------------------------------- ConvLSTM cell
struct CellArgs {
  const float* x[2]; long xbs;
  const float* h[2]; const float* c[2];
  const float* w[2]; const float* bias[2];   // w transposed [ic*9+t][256]
  float* ho[2]; float* co[2];
};

template<int CX>
__global__ __launch_bounds__(512) void cell_kernel(CellArgs a) {
  constexpr int CT = CX + HIDC;
  constexpr int CH = (CT + 1) / 2;
  __shared__ float sIn[CT * 48];
  __shared__ float sGa[256 * 17];
  __shared__ float sGb[256 * 17];
  const int tile = blockIdx.x;
  const int b = blockIdx.y;
  const int st = blockIdx.z;
  const int ty0 = (tile >> 3) << 2, tx0 = (tile & 7) << 2;
  const float* xp = a.x[st] + (size_t)b * a.xbs;
  const float* hp = a.h[st] + (size_t)b * HIDC * HWN;

  for (int idx = threadIdx.x; idx < CT * 36; idx += 512) {
    int ic = idx / 36, pos = idx - ic * 36;
    int iy = pos / 6, ix = pos - iy * 6;
    int gy = ty0 - 1 + iy, gx = tx0 - 1 + ix;
    float v = 0.f;
    if ((unsigned)gy < 32u && (unsigned)gx < 32u) {
      v = (ic < CX) ? xp[ic * HWN + gy * 32 + gx]
                    : hp[(ic - CX) * HWN + gy * 32 + gx];
    }
    sIn[ic * 48 + iy * 8 + ix] = v;
  }
  __syncthreads();

  const int oc = threadIdx.x & 255;
  const int hh = threadIdx.x >> 8;
  const int icb = hh ? CH : 0, ice = hh ? CT : CH;
  float acc[16];
#pragma unroll
  for (int p = 0; p < 16; ++p) acc[p] = 0.f;
  const float* wp = a.w[st];
  for (int ic = icb; ic < ice; ++ic) {
    float w9[9];
#pragma unroll
    for (int t = 0; t < 9; ++t) w9[t] = wp[(ic * 9 + t) * 256 + oc];
    float in[36];
#pragma unroll
    for (int iy = 0; iy < 6; ++iy) {
      float4 v4 = *(const float4*)&sIn[ic * 48 + iy * 8];
      float2 v2 = *(const float2*)&sIn[ic * 48 + iy * 8 + 4];
      in[iy * 6 + 0] = v4.x; in[iy * 6 + 1] = v4.y; in[iy * 6 + 2] = v4.z;
      in[iy * 6 + 3] = v4.w; in[iy * 6 + 4] = v2.x; in[iy * 6 + 5] = v2.y;
    }
#pragma unroll
    for (int ky = 0; ky < 3; ++ky)
#pragma unroll
      for (int kx = 0; kx < 3; ++kx) {
        const float wv = w9[ky * 3 + kx];
#pragma unroll
        for (int py = 0; py < 4; ++py)
#pragma unroll
          for (int px = 0; px < 4; ++px)
            acc[py * 4 + px] += wv * in[(py + ky) * 6 + (px + kx)];
      }
  }
  float* sGh = hh ? sGb : sGa;
#pragma unroll
  for (int p = 0; p < 16; ++p) sGh[oc * 17 + p] = acc[p];
  __syncthreads();

  const float* cp = a.c[st] + (size_t)b * HIDC * HWN;
  float* hop = a.ho[st] + (size_t)b * HIDC * HWN;
  float* cop = a.co[st] + (size_t)b * HIDC * HWN;
  const float* bias = a.bias[st];
  for (int idx = threadIdx.x; idx < HIDC * 16; idx += 512) {
    int hc = idx >> 4, p = idx & 15;
    float gi = sGa[hc * 17 + p]         + sGb[hc * 17 + p]         + bias[hc];
    float gf = sGa[(hc + 64) * 17 + p]  + sGb[(hc + 64) * 17 + p]  + bias[hc + 64];
    float go = sGa[(hc + 128) * 17 + p] + sGb[(hc + 128) * 17 + p] + bias[hc + 128];
    float gg = sGa[(hc + 192) * 17 + p] + sGb[(hc + 192) * 17 + p] + bias[hc + 192];
    gi = 1.f / (1.f + expf(-gi));
    gf = 1.f / (1.f + expf(-gf));
    go = 1.f / (1.f + expf(-go));
    gg = tanhf(gg);
    int off = hc * HWN + (ty0 + (p >> 2)) * 32 + tx0 + (p & 3);
    float cn = gf * cp[off] + gi * gg;
    cop[off] = cn;
    hop[off] = go * tanhf(cn);
  }
}

// ---------------------------------------------------------------- QKV (1x1 convs) -> fp16 hi/lo
struct QkvArgs {
  const float* xq[4]; const float* xkv[4];
  const float* w[4]; const float* bias[4];
  unsigned short *Qh, *Ql, *Kh, *Kl, *Vth, *Vtl;
};

__global__ __launch_bounds__(256) void qkv_kernel(QkvArgs a) {
  __shared__ float sWt[64 * 68];
  const int ptile = blockIdx.x, b = blockIdx.y;
  const int attn = blockIdx.z / 3, proj = blockIdx.z % 3;
  const float* x = (proj == 0 ? a.xq[attn] : a.xkv[attn]) + (size_t)b * HIDC * HWN;
  const float* w = a.w[attn] + proj * 64 * 64;
  const float* bias = a.bias[attn] + proj * 64;
  const size_t bb = (size_t)attn * BB + b;
  for (int i = threadIdx.x; i < 4096; i += 256) {
    int o = i >> 6, c = i & 63;
    sWt[c * 68 + o] = w[i];
  }
  __syncthreads();
  const int pq = threadIdx.x & 63, og = threadIdx.x >> 6;
  const int p0 = ptile * 64 + pq;
  float acc[16];
#pragma unroll
  for (int k = 0; k < 16; ++k) acc[k] = bias[og * 16 + k];
  for (int c = 0; c < 64; ++c) {
    float xv = x[c * HWN + p0];
#pragma unroll
    for (int k = 0; k < 16; k += 4) {
      float4 wv = *(const float4*)&sWt[c * 68 + og * 16 + k];
      acc[k+0] += xv * wv.x; acc[k+1] += xv * wv.y;
      acc[k+2] += xv * wv.z; acc[k+3] += xv * wv.w;
    }
  }
  if (proj <= 1) {
    const float sc = (proj == 0) ? 0.125f : 1.f;
    unsigned short* dh = (proj == 0 ? a.Qh : a.Kh) + (bb << 16) + p0 * 64 + og * 16;
    unsigned short* dl = (proj == 0 ? a.Ql : a.Kl) + (bb << 16) + p0 * 64 + og * 16;
#pragma unroll
    for (int k = 0; k < 16; k += 2) {
      float v0 = acc[k] * sc, v1 = acc[k+1] * sc;
      unsigned short h0 = f2h_bits(v0), h1 = f2h_bits(v1);
      *(unsigned int*)&dh[k] = (unsigned int)h0 | ((unsigned int)h1 << 16);
      unsigned short l0 = f2h_bits(v0 - h_back(v0)), l1 = f2h_bits(v1 - h_back(v1));
      *(unsigned int*)&dl[k] = (unsigned int)l0 | ((unsigned int)l1 << 16);
    }
  } else {
    unsigned short* dvh = a.Vth + (bb << 16);
    unsigned short* dvl = a.Vtl + (bb << 16);
#pragma unroll
    for (int k = 0; k < 16; ++k) {
      float v = acc[k];
      dvh[(size_t)(og * 16 + k) * HWN + p0] = f2h_bits(v);
      dvl[(size_t)(og * 16 + k) * HWN + p0] = f2h_bits(v - h_back(v));
    }
  }
}

// ---------------------------------------------------------------- MFMA flash attention (split-fp16)
// S^T = K.Q^T via mfma_f32_16x16x32_f16 (A=K rows, B=Q rows; D col=lane&15=q).
// Softmax fully lane-local per q; PV as O^T = V^T.P^T (A=Vt rows, B=P from LDS).
struct AttnPArgs {
  const unsigned short *Qh, *Ql, *Kh, *Kl, *Vth, *Vtl;
  float* pbuf;
};

__global__ __launch_bounds__(256) void attn_part(AttnPArgs a) {
  __shared__ unsigned short sP[4][2][16][72];   // [wave][hi/lo][q][j pad72, XOR-swz]
  const int qt = blockIdx.x >> 2, ks = blockIdx.x & 3;
  const int b = blockIdx.y, at = blockIdx.z;
  const size_t bb = (size_t)at * BB + b;
  const int tid = threadIdx.x;
  const int w = tid >> 6, lane = tid & 63;
  const int g = lane >> 4, qc = lane & 15;
  const int swz = (qc & 7) << 3;
  const unsigned short* Qhp = a.Qh + (bb << 16);
  const unsigned short* Qlp = a.Ql + (bb << 16);
  const unsigned short* Khp = a.Kh + (bb << 16);
  const unsigned short* Klp = a.Kl + (bb << 16);
  const unsigned short* Vhp = a.Vth + (bb << 16);
  const unsigned short* Vlp = a.Vtl + (bb << 16);

  const int qrow = qt * 64 + w * 16 + qc;       // B col for S^T
  const half8 bqh0 = *(const half8*)&Qhp[qrow * 64 + 0  + g * 8];
  const half8 bqh1 = *(const half8*)&Qhp[qrow * 64 + 32 + g * 8];
  const half8 bql0 = *(const half8*)&Qlp[qrow * 64 + 0  + g * 8];
  const half8 bql1 = *(const half8*)&Qlp[qrow * 64 + 32 + g * 8];

  float mrun = -1e30f, lrun = 0.f;
  f32x4 sO[4];
#pragma unroll
  for (int i = 0; i < 4; ++i) sO[i] = (f32x4)0.f;

  for (int kk = 0; kk < 4; ++kk) {
    const int jt = (ks * 4 + kk) * 64;
    f32x4 sS[4];
#pragma unroll
    for (int i = 0; i < 4; ++i) sS[i] = (f32x4)0.f;
#pragma unroll
    for (int sb = 0; sb < 4; ++sb) {
      const int j = jt + sb * 16 + qc;          // A row
      const half8 ah0 = *(const half8*)&Khp[j * 64 + 0  + g * 8];
      const half8 ah1 = *(const half8*)&Khp[j * 64 + 32 + g * 8];
      const half8 al0 = *(const half8*)&Klp[j * 64 + 0  + g * 8];
      const half8 al1 = *(const half8*)&Klp[j * 64 + 32 + g * 8];
      f32x4 d = sS[sb];
      d = __builtin_amdgcn_mfma_f32_16x16x32_f16(ah0, bqh0, d, 0, 0, 0);
      d = __builtin_amdgcn_mfma_f32_16x16x32_f16(ah1, bqh1, d, 0, 0, 0);
      d = __builtin_amdgcn_mfma_f32_16x16x32_f16(ah0, bql0, d, 0, 0, 0);
      d = __builtin_amdgcn_mfma_f32_16x16x32_f16(ah1, bql1, d, 0, 0, 0);
      d = __builtin_amdgcn_mfma_f32_16x16x32_f16(al0, bqh0, d, 0, 0, 0);
      d = __builtin_amdgcn_mfma_f32_16x16x32_f16(al1, bqh1, d, 0, 0, 0);
      sS[sb] = d;
    }
    // ---- lane-local softmax (each lane: 16 j-values for its single q) ----
    float mt = -1e30f;
#pragma unroll
    for (int sb = 0; sb < 4; ++sb)
#pragma unroll
      for (int r = 0; r < 4; ++r) mt = fmaxf(mt, sS[sb][r]);
    mt = fmaxf(mt, __shfl_xor(mt, 16));
    mt = fmaxf(mt, __shfl_xor(mt, 32));
    const float mn = fmaxf(mrun, mt);
    const float al = __expf(mrun - mn);
    float p[16];
    float ps = 0.f;
#pragma unroll
    for (int sb = 0; sb < 4; ++sb)
#pragma unroll
      for (int r = 0; r < 4; ++r) {
        float e = __expf(sS[sb][r] - mn);
        p[sb * 4 + r] = e; ps += e;
      }
    ps += __shfl_xor(ps, 16);
    ps += __shfl_xor(ps, 32);
    lrun = lrun * al + ps;
    mrun = mn;
#pragma unroll
    for (int i = 0; i < 4; ++i) {
      sO[i][0] *= al; sO[i][1] *= al; sO[i][2] *= al; sO[i][3] *= al;
    }
    // ---- P -> fp16 hi/lo -> per-wave LDS (no barrier: wave-private region) ----
#pragma unroll
    for (int sb = 0; sb < 4; ++sb)
#pragma unroll
      for (int rp = 0; rp < 4; rp += 2) {
        int j = sb * 16 + g * 4 + rp;           // even
        int js = j ^ swz;
        float v0 = p[sb * 4 + rp], v1 = p[sb * 4 + rp + 1];
        unsigned short h0 = f2h_bits(v0), h1 = f2h_bits(v1);
        *(unsigned int*)&sP[w][0][qc][js] = (unsigned int)h0 | ((unsigned int)h1 << 16);
        unsigned short l0 = f2h_bits(v0 - h_back(v0)), l1 = f2h_bits(v1 - h_back(v1));
        *(unsigned int*)&sP[w][1][qc][js] = (unsigned int)l0 | ((unsigned int)l1 << 16);
      }
    const half8 ph0 = *(const half8*)&sP[w][0][qc][((0 + g) ^ (qc & 7)) * 8];
    const half8 ph1 = *(const half8*)&sP[w][0][qc][((4 + g) ^ (qc & 7)) * 8];
    const half8 pl0 = *(const half8*)&sP[w][1][qc][((0 + g) ^ (qc & 7)) * 8];
    const half8 pl1 = *(const half8*)&sP[w][1][qc][((4 + g) ^ (qc & 7)) * 8];
    // ---- PV: O^T += V^T . P^T ----
#pragma unroll
    for (int vs = 0; vs < 4; ++vs) {
      const int vc = vs * 16 + qc;              // A row
      const half8 vh0 = *(const half8*)&Vhp[(size_t)vc * HWN + jt + 0  + g * 8];
      const half8 vh1 = *(const half8*)&Vhp[(size_t)vc * HWN + jt + 32 + g * 8];
      const half8 vl0 = *(const half8*)&Vlp[(size_t)vc * HWN + jt + 0  + g * 8];
      const half8 vl1 = *(const half8*)&Vlp[(size_t)vc * HWN + jt + 32 + g * 8];
      f32x4 d = sO[vs];
      d = __builtin_amdgcn_mfma_f32_16x16x32_f16(vh0, ph0, d, 0, 0, 0);
      d = __builtin_amdgcn_mfma_f32_16x16x32_f16(vh1, ph1, d, 0, 0, 0);
      d = __builtin_amdgcn_mfma_f32_16x16x32_f16(vh0, pl0, d, 0, 0, 0);
      d = __builtin_amdgcn_mfma_f32_16x16x32_f16(vh1, pl1, d, 0, 0, 0);
      d = __builtin_amdgcn_mfma_f32_16x16x32_f16(vl0, ph0, d, 0, 0, 0);
      d = __builtin_amdgcn_mfma_f32_16x16x32_f16(vl1, ph1, d, 0, 0, 0);
      sO[vs] = d;
    }
  }
  // partial record: [64q x 64c o][64 m][64 l] = 4224 floats
  float* pb = a.pbuf + ((bb * 16 + qt) * 4 + ks) * 4224;
  const int qloc = w * 16 + qc;
#pragma unroll
  for (int vs = 0; vs < 4; ++vs)
#pragma unroll
    for (int r = 0; r < 4; ++r)
      pb[qloc * 64 + vs * 16 + g * 4 + r] = sO[vs][r];
  if (g == 0) {
    pb[4096 + qloc] = mrun;
    pb[4160 + qloc] = lrun;
  }
}

struct AttnMArgs { const float* pbuf; const float* xq[4]; float* out[4]; };

__global__ __launch_bounds__(256) void attn_merge(AttnMArgs a) {
  __shared__ float sW[4][64];
  __shared__ float sL[64];
  const int qt = blockIdx.x, b = blockIdx.y, at = blockIdx.z;
  const float* pb = a.pbuf + (((size_t)at * BB + b) * 16 + qt) * 4 * 4224;
  if (threadIdx.x < 64) {
    int r = threadIdx.x;
    float mm[4];
#pragma unroll
    for (int i = 0; i < 4; ++i) mm[i] = pb[i * 4224 + 4096 + r];
    float M = fmaxf(fmaxf(mm[0], mm[1]), fmaxf(mm[2], mm[3]));
    float L = 0.f;
#pragma unroll
    for (int i = 0; i < 4; ++i) {
      float wv = __expf(mm[i] - M);
      sW[i][r] = wv;
      L += pb[i * 4224 + 4160 + r] * wv;
    }
    sL[r] = L;
  }
  __syncthreads();
  const int c = threadIdx.x >> 2, rg = (threadIdx.x & 3) * 16;
  const float* xq = a.xq[at] + (size_t)b * HIDC * HWN;
  float* op = a.out[at] + (size_t)b * HIDC * HWN;
  const int p0 = qt * 64 + rg;
#pragma unroll
  for (int rr4 = 0; rr4 < 16; rr4 += 4) {
    float rv[4];
#pragma unroll
    for (int k = 0; k < 4; ++k) {
      int r = rg + rr4 + k;
      float acc = 0.f;
#pragma unroll
      for (int i = 0; i < 4; ++i) acc += pb[i * 4224 + r * 64 + c] * sW[i][r];
      rv[k] = acc / sL[r];
    }
    float4 x4 = *(const float4*)&xq[(size_t)c * HWN + p0 + rr4];
    float4 res; res.x = rv[0] + x4.x; res.y = rv[1] + x4.y;
    res.z = rv[2] + x4.z; res.w = rv[3] + x4.w;
    *(float4*)&op[(size_t)c * HWN + p0 + rr4] = res;
  }
}

// ---------------------------------------------------------------- decoder
struct Dec1Args { const float* in[2]; const float* w; const float* b; float* tmp; };

__global__ __launch_bounds__(512) void dec1_kernel(Dec1Args a) {
  __shared__ float sIn[64 * 48];
  __shared__ float sHa[64 * 17];
  __shared__ float sHb[64 * 17];
  const int tile = blockIdx.x, b = blockIdx.y, st = blockIdx.z;
  const int ty0 = (tile >> 3) << 2, tx0 = (tile & 7) << 2;
  const float* ip = a.in[st] + (size_t)b * HIDC * HWN;
  for (int idx = threadIdx.x; idx < 64 * 36; idx += 512) {
    int ic = idx / 36, pos = idx - ic * 36;
    int iy = pos / 6, ix = pos - iy * 6;
    int gy = ty0 - 1 + iy, gx = tx0 - 1 + ix;
    float v = 0.f;
    if ((unsigned)gy < 32u && (unsigned)gx < 32u) v = ip[ic * HWN + gy * 32 + gx];
    sIn[ic * 48 + iy * 8 + ix] = v;
  }
  __syncthreads();
  const int oc = threadIdx.x & 63, ps = (threadIdx.x >> 6) & 3;
  const int hh = threadIdx.x >> 8;
  const int icb = hh * 32, ice = icb + 32;
  float acc0 = 0.f, acc1 = 0.f, acc2 = 0.f, acc3 = 0.f;
  const float* wp = a.w;
  for (int ic = icb; ic < ice; ++ic) {
    float w9[9];
#pragma unroll
    for (int t = 0; t < 9; ++t) w9[t] = wp[(ic * 9 + t) * 64 + oc];
    float in[18];
#pragma unroll
    for (int ry = 0; ry < 3; ++ry) {
      float4 v4 = *(const float4*)&sIn[ic * 48 + (ps + ry) * 8];
      float2 v2 = *(const float2*)&sIn[ic * 48 + (ps + ry) * 8 + 4];
      in[ry*6+0]=v4.x; in[ry*6+1]=v4.y; in[ry*6+2]=v4.z; in[ry*6+3]=v4.w;
      in[ry*6+4]=v2.x; in[ry*6+5]=v2.y;
    }
#pragma unroll
    for (int ky = 0; ky < 3; ++ky)
#pragma unroll
      for (int kx = 0; kx < 3; ++kx) {
        float wv = w9[ky * 3 + kx];
        acc0 += wv * in[ky * 6 + kx + 0];
        acc1 += wv * in[ky * 6 + kx + 1];
        acc2 += wv * in[ky * 6 + kx + 2];
        acc3 += wv * in[ky * 6 + kx + 3];
      }
  }
  float* sH = hh ? sHb : sHa;
  sH[oc * 17 + ps * 4 + 0] = acc0;
  sH[oc * 17 + ps * 4 + 1] = acc1;
  sH[oc * 17 + ps * 4 + 2] = acc2;
  sH[oc * 17 + ps * 4 + 3] = acc3;
  __syncthreads();
  float* dst = a.tmp + ((size_t)st * BB + b) * HIDC * HWN;
  for (int idx = threadIdx.x; idx < 1024; idx += 512) {
    int oc2 = idx >> 4, p = idx & 15;
    float v = sHa[oc2 * 17 + p] + sHb[oc2 * 17 + p] + a.b[oc2];
    v = fmaxf(v, 0.f);
    dst[(size_t)oc2 * HWN + (ty0 + (p >> 2)) * 32 + tx0 + (p & 3)] = v;
  }
}

struct Dec2Args { const float* tmp; const float* w; const float* b;
                  float* dst0; float* dst1; long bstr; };

__global__ __launch_bounds__(256) void dec2_kernel(Dec2Args a) {
  __shared__ float sIn[64 * 48];
  __shared__ float sW[64 * 9];
  const int tile = blockIdx.x, b = blockIdx.y, st = blockIdx.z;
  const int ty0 = (tile >> 3) << 2, tx0 = (tile & 7) << 2;
  const float* ip = a.tmp + ((size_t)st * BB + b) * HIDC * HWN;
  for (int idx = threadIdx.x; idx < 64 * 36; idx += 256) {
    int ic = idx / 36, pos = idx - ic * 36;
    int iy = pos / 6, ix = pos - iy * 6;
    int gy = ty0 - 1 + iy, gx = tx0 - 1 + ix;
    float v = 0.f;
    if ((unsigned)gy < 32u && (unsigned)gx < 32u) v = ip[ic * HWN + gy * 32 + gx];
    sIn[ic * 48 + iy * 8 + ix] = v;
  }
  for (int idx = threadIdx.x; idx < 576; idx += 256) sW[idx] = a.w[idx];
  __syncthreads();
  const int px = threadIdx.x >> 4, icg = threadIdx.x & 15;
  const int py = px >> 2, pxx = px & 3;
  float acc = 0.f;
#pragma unroll
  for (int i = 0; i < 4; ++i) {
    int ic = icg * 4 + i;
    const float* row = &sIn[ic * 48];
    const float* wv = &sW[ic * 9];
#pragma unroll
    for (int ky = 0; ky < 3; ++ky)
#pragma unroll
      for (int kx = 0; kx < 3; ++kx)
        acc += wv[ky * 3 + kx] * row[(py + ky) * 8 + pxx + kx];
  }
#pragma unroll
  for (int d = 1; d < 16; d <<= 1) acc += __shfl_xor(acc, d);
  if (icg == 0) {
    float* d = (st == 0 ? a.dst0 : a.dst1);
    d[(size_t)b * a.bstr + (ty0 + py) * 32 + tx0 + pxx] = acc + a.b[0];
  }
}

// ---------------------------------------------------------------- host
extern "C" void kernel_launch(void* const* d_in, const int* in_sizes, int n_in,
                              void* d_out, int out_size, void* d_ws, size_t ws_size,
                              hipStream_t stream) {
  (void)in_sizes; (void)n_in; (void)out_size; (void)ws_size;
  const float* x1_seq = (const float*)d_in[0];
  const float* x2_seq = (const float*)d_in[1];
  const float* c1w[2] = {(const float*)d_in[2], (const float*)d_in[4]};
  const float* c1b[2] = {(const float*)d_in[3], (const float*)d_in[5]};
  const float* c2w[2] = {(const float*)d_in[6], (const float*)d_in[8]};
  const float* c2b[2] = {(const float*)d_in[7], (const float*)d_in[9]};
  const float* sah_w = (const float*)d_in[10]; const float* sah_b = (const float*)d_in[11];
  const float* sac_w = (const float*)d_in[12]; const float* sac_b = (const float*)d_in[13];
  const float* cah_w = (const float*)d_in[14]; const float* cah_b = (const float*)d_in[15];
  const float* cac_w = (const float*)d_in[16]; const float* cac_b = (const float*)d_in[17];
  const float* dw1 = (const float*)d_in[18]; const float* db1 = (const float*)d_in[19];
  const float* dw2 = (const float*)d_in[20]; const float* db2 = (const float*)d_in[21];
  float* out = (float*)d_out;
  float* ws = (float*)d_ws;

  const size_t SPL = (size_t)BB * HIDC * HWN;   // 131072 floats
  float* h1s = ws;
  float* c1s = h1s + 2 * SPL;
  float* h2s = c1s + 2 * SPL;
  float* c2s = h2s + 2 * SPL;
  float* hc1 = c2s + 2 * SPL;
  float* cc1 = hc1 + SPL;
  float* hc2 = cc1 + SPL;
  float* cc2 = hc2 + SPL;
  float* hs1 = cc2 + SPL;
  float* cs1 = hs1 + SPL;
  float* hs2 = cs1 + SPL;
  float* cs2 = hs2 + SPL;
  float* Qf  = cs2 + SPL;         // 4 SPL floats -> Qh/Ql (u16)
  float* Kf  = Qf + 4 * SPL;      // 4 SPL floats -> Kh/Kl
  float* Vf  = Kf + 4 * SPL;      // 4 SPL floats -> Vth/Vtl
  unsigned short* Qh = (unsigned short*)Qf;  unsigned short* Ql = Qh + (size_t)8 * 65536;
  unsigned short* Kh = (unsigned short*)Kf;  unsigned short* Kl = Kh + (size_t)8 * 65536;
  unsigned short* Vth = (unsigned short*)Vf; unsigned short* Vtl = Vth + (size_t)8 * 65536;
  float* dtmp = Vf + 4 * SPL;     // [2][B][64][1024]
  float* pbuf = dtmp + 2 * SPL;   // [8bb][16qt][4ks][4224] = ~8.7 MB
  float* wt10 = pbuf + (size_t)4 * BB * 16 * 4 * 4224;
  float* wt11 = wt10 + 585 * 256;
  float* wt20 = wt11 + 1152 * 256;
  float* wt21 = wt20 + 585 * 256;
  float* wtd  = wt21 + 1152 * 256;

  hipMemsetAsync(ws, 0, 8 * SPL * sizeof(float), stream);  // zero states

  const dim3 blk(256);
  const dim3 blk2(512);

  {
    TWArgs tw;
    tw.src[0] = c1w[0]; tw.dst[0] = wt10; tw.icn9[0] = 585;  tw.osh[0] = 8;
    tw.src[1] = c1w[1]; tw.dst[1] = wt11; tw.icn9[1] = 1152; tw.osh[1] = 8;
    tw.src[2] = c2w[0]; tw.dst[2] = wt20; tw.icn9[2] = 585;  tw.osh[2] = 8;
    tw.src[3] = c2w[1]; tw.dst[3] = wt21; tw.icn9[3] = 1152; tw.osh[3] = 8;
    tw.src[4] = dw1;    tw.dst[4] = wtd;  tw.icn9[4] = 576;  tw.osh[4] = 6;
    transpose_w<<<dim3(32, 5), blk, 0, stream>>>(tw);
  }

  auto attn_stage = [&](const float* q0, const float* q1, const float* q2, const float* q3,
                        const float* k0, const float* k1, const float* k2, const float* k3,
                        const float* wh, const float* bh, const float* wc, const float* bc,
                        float* o0, float* o1, float* o2, float* o3) {
    QkvArgs qa;
    qa.xq[0]=q0; qa.xq[1]=q1; qa.xq[2]=q2; qa.xq[3]=q3;
    qa.xkv[0]=k0; qa.xkv[1]=k1; qa.xkv[2]=k2; qa.xkv[3]=k3;
    qa.w[0]=wh; qa.w[1]=wc; qa.w[2]=wh; qa.w[3]=wc;
    qa.bias[0]=bh; qa.bias[1]=bc; qa.bias[2]=bh; qa.bias[3]=bc;
    qa.Qh=Qh; qa.Ql=Ql; qa.Kh=Kh; qa.Kl=Kl; qa.Vth=Vth; qa.Vtl=Vtl;
    qkv_kernel<<<dim3(16, BB, 12), blk, 0, stream>>>(qa);
    AttnPArgs ap; ap.Qh=Qh; ap.Ql=Ql; ap.Kh=Kh; ap.Kl=Kl; ap.Vth=Vth; ap.Vtl=Vtl;
    ap.pbuf=pbuf;
    attn_part<<<dim3(64, BB, 4), blk, 0, stream>>>(ap);
    AttnMArgs am; am.pbuf=pbuf;
    am.xq[0]=q0; am.xq[1]=q1; am.xq[2]=q2; am.xq[3]=q3;
    am.out[0]=o0; am.out[1]=o1; am.out[2]=o2; am.out[3]=o3;
    attn_merge<<<dim3(16, BB, 4), blk, 0, stream>>>(am);
  };

  auto decode = [&](long off1, long off2, long bstr) {
    Dec1Args d1; d1.in[0] = h1s + SPL; d1.in[1] = h2s + SPL;
    d1.w = wtd; d1.b = db1; d1.tmp = dtmp;
    dec1_kernel<<<dim3(64, BB, 2), blk2, 0, stream>>>(d1);
    Dec2Args d2; d2.tmp = dtmp; d2.w = dw2; d2.b = db2;
    d2.dst0 = out + off1; d2.dst1 = out + off2; d2.bstr = bstr;
    dec2_kernel<<<dim3(64, BB, 2), blk, 0, stream>>>(d2);
  };

  for (int s = 0; s < 6; ++s) {
    const float *x1, *x2; long xbs;
    if (s < 3) { x1 = x1_seq + s * HWN; x2 = x2_seq + s * HWN; xbs = 3 * HWN; }
    else       { x1 = out + (s - 3) * HWN; x2 = out + 8192 + (s - 3) * HWN; xbs = 4 * HWN; }

    for (int l = 0; l < 2; ++l) {
      if (l == 1) { x1 = h1s; x2 = h2s; xbs = (long)HIDC * HWN; }
      CellArgs ca;
      ca.x[0] = x1; ca.x[1] = x2; ca.xbs = xbs;
      ca.h[0] = h1s + l * SPL; ca.h[1] = h2s + l * SPL;
      ca.c[0] = c1s + l * SPL; ca.c[1] = c2s + l * SPL;
      ca.w[0] = (l == 0) ? wt10 : wt11;
      ca.w[1] = (l == 0) ? wt20 : wt21;
      ca.bias[0] = c1b[l]; ca.bias[1] = c2b[l];
      ca.ho[0] = hc1; ca.ho[1] = hc2; ca.co[0] = cc1; ca.co[1] = cc2;
      if (l == 0) cell_kernel<1><<<dim3(64, BB, 2), blk2, 0, stream>>>(ca);
      else        cell_kernel<64><<<dim3(64, BB, 2), blk2, 0, stream>>>(ca);

      attn_stage(hc1, cc1, hc2, cc2,
                 hc1, cc1, hc2, cc2,
                 sah_w + l * 12288, sah_b + l * 192,
                 sac_w + l * 12288, sac_b + l * 192,
                 hs1, cs1, hs2, cs2);
      attn_stage(hs1, cs1, hs2, cs2,
                 hs2, cs2, hs1, cs1,
                 cah_w + l * 12288, cah_b + l * 192,
                 cac_w + l * 12288, cac_b + l * 192,
                 h1s + l * SPL, c1s + l * SPL, h2s + l * SPL, c2s + l * SPL);
    }

    if (s == 0)      decode(16384,        20480,        2048);
    else if (s == 1) decode(16384 + 1024, 20480 + 1024, 2048);
    else             decode((s - 2) * HWN, 8192 + (s - 2) * HWN, 4096);
  }
}